// Round 17
// baseline (84.509 us; speedup 1.0000x reference)
//
#include <hip/hip_runtime.h>
#include <math.h>

// Problem constants (CapsNet routing)
#define BB   256   // batch
#define NI   1152  // input capsules
#define DI   8     // input dim
#define NJ   10    // output capsules
#define DJ   16    // output dim
#define NCHUNK 18  // NI / CHUNK
#define CHUNK  64  // i per block
#define BG     32  // batch per block
#define NBG    8   // BB / BG
#define GRID_MAIN (NJ * NCHUNK * NBG)   // 1440 = 8 XCD x 180
#define CTP  66    // ctile row stride (f32): conflict-free + float2-aligned

typedef _Float16 half2_t __attribute__((ext_vector_type(2)));
typedef _Float16 half4_t __attribute__((ext_vector_type(4)));
typedef _Float16 half8_t __attribute__((ext_vector_type(8)));
typedef float    f32x4   __attribute__((ext_vector_type(4)));

// DPP cross-lane adds (VALU pipe, no LDS traffic)
// 0x124 row_ror:4, 0x128 row_ror:8 (16-lane row); 0x0B1 quad lane^1, 0x04E quad lane^2
template <int CTRL>
__device__ __forceinline__ float dpp_add(float x) {
    int xi = __float_as_int(x);
    int yi = __builtin_amdgcn_update_dpp(0, xi, CTRL, 0xF, 0xF, true);
    return x + __int_as_float(yi);
}

// f16 dot-8 with f32 accumulation: 4 chained v_dot2_f32_f16 (BV path)
__device__ __forceinline__ float dot16(half8_t w, half8_t uu) {
    half2_t w0 = {w[0], w[1]}, w1 = {w[2], w[3]}, w2 = {w[4], w[5]}, w3 = {w[6], w[7]};
    half2_t a0 = {uu[0], uu[1]}, a1 = {uu[2], uu[3]}, a2 = {uu[4], uu[5]}, a3 = {uu[6], uu[7]};
    float acc = __builtin_amdgcn_fdot2(w0, a0, 0.f, false);
    acc = __builtin_amdgcn_fdot2(w1, a1, acc, false);
    acc = __builtin_amdgcn_fdot2(w2, a2, acc, false);
    acc = __builtin_amdgcn_fdot2(w3, a3, acc, false);
    return acc;
}

struct Ctx {
    int j, chunk, bg, i0, b0, tid, il, dq, lane, w, g, xcd, local;
};

// XCD-bijective swizzle: xcd = bid&7 owns local 0..179 -> bg == xcd, all (j,chunk).
__device__ __forceinline__ Ctx make_ctx(int bid, int tid) {
    Ctx c;
    c.xcd = bid & 7; c.local = bid >> 3;
    int gx = c.xcd * (GRID_MAIN / 8) + c.local;
    c.j = gx % NJ; int r = gx / NJ;
    c.chunk = r % NCHUNK; c.bg = r / NCHUNK;   // bg == xcd by construction
    c.i0 = c.chunk * CHUNK; c.b0 = c.bg * BG;
    c.tid = tid; c.il = tid >> 2; c.dq = tid & 3;
    c.lane = tid & 63; c.w = tid >> 6; c.g = (c.lane >> 4) & 3;
    return c;
}

// W16[j, i0+il, dq*4+q, 0..7] : 4 x half8 (16 VGPR), BV layout
__device__ __forceinline__ void loadW16(const _Float16* __restrict__ W16, const Ctx& cx,
                                        half8_t* Wh) {
    const half8_t* wp = (const half8_t*)(W16 +
        (((size_t)cx.j * NI + cx.i0 + cx.il) * DJ + cx.dq * 4) * DI);
#pragma unroll
    for (int q = 0; q < 4; ++q) Wh[q] = wp[q];
}

// MFMA-layout W fragment: Wf[qq] = W16[j, i0 + w*16 + qq*4 + ksub, drow, 0..7]
__device__ __forceinline__ void loadWf(const _Float16* __restrict__ W16, const Ctx& cx,
                                       half8_t* Wf) {
    int drow = cx.lane & 15, ksub = cx.lane >> 4;
#pragma unroll
    for (int qq = 0; qq < 4; ++qq) {
        int i = cx.i0 + cx.w * 16 + qq * 4 + ksub;
        Wf[qq] = *(const half8_t*)(W16 + (((size_t)cx.j * NI + i) * DJ + drow) * DI);
    }
}

// ---- f32 -> f16 conversion, 4 float4 per thread (grid 936) ----
__global__ __launch_bounds__(256) void k_cvt(const float* __restrict__ uf,
                                             const float* __restrict__ Wf,
                                             _Float16* __restrict__ u16,
                                             _Float16* __restrict__ W16) {
    const int nu4 = (BB * NI * DI) / 4;        // 589824 (divisible by 4)
    int base = (blockIdx.x * 256 + threadIdx.x) * 4;
    if (base < nu4) {
#pragma unroll
        for (int t = 0; t < 4; ++t) {
            float4 v = ((const float4*)uf)[base + t];
            half4_t h = {(_Float16)v.x, (_Float16)v.y, (_Float16)v.z, (_Float16)v.w};
            ((half4_t*)u16)[base + t] = h;
        }
    } else {
        int k = base - nu4;
#pragma unroll
        for (int t = 0; t < 4; ++t) {
            float4 v = ((const float4*)Wf)[k + t];
            half4_t h = {(_Float16)v.x, (_Float16)v.y, (_Float16)v.z, (_Float16)v.w};
            ((half4_t*)W16)[k + t] = h;
        }
    }
}

// ---- MFMA A core for iter 0 (c = 0.1 exact at epilogue) ----
__device__ __forceinline__ void phaseAm0(const Ctx& cx, const _Float16* __restrict__ u16,
                                         float* __restrict__ spart,
                                         const half8_t* Wf, float* sres2) {
    int l = cx.lane, w = cx.w;
    int drow = l & 15, ksub = l >> 4;

    half8_t au[2][4];
#pragma unroll
    for (int h = 0; h < 2; ++h) {
        int b = cx.b0 + h * 16 + drow;
#pragma unroll
        for (int qq = 0; qq < 4; ++qq) {
            int il = w * 16 + qq * 4 + ksub;
            au[h][qq] = *(const half8_t*)(u16 + ((size_t)b * NI + cx.i0 + il) * DI);
        }
    }

#pragma unroll
    for (int h = 0; h < 2; ++h) {
        f32x4 acc = {0.f, 0.f, 0.f, 0.f};
#pragma unroll
        for (int qq = 0; qq < 4; ++qq)
            acc = __builtin_amdgcn_mfma_f32_16x16x32_f16(au[h][qq], Wf[qq], acc, 0, 0, 0);
#pragma unroll
        for (int r = 0; r < 4; ++r)
            sres2[((h * 4 + w) * 16 + ksub * 4 + r) * 17 + drow] = acc[r];
    }
    __syncthreads();

#pragma unroll
    for (int p = 0; p < 2; ++p) {
        int idx = p * 256 + cx.tid;
        int d = idx & 15, brow = (idx >> 4) & 15, h = idx >> 8;
        float s = 0.f;
#pragma unroll
        for (int w2 = 0; w2 < 4; ++w2)
            s += sres2[((h * 4 + w2) * 16 + brow) * 17 + d];
        s *= 0.1f;                           // exact c=0.1 (softmax of zeros)
        spart[(((size_t)cx.chunk * BB + cx.b0 + h * 16 + brow) * NJ + cx.j) * DJ + d] = s;
    }
}

// ---- k_A0m ----
__global__ __launch_bounds__(256) void k_A0m(const _Float16* __restrict__ u16,
                                             const _Float16* __restrict__ W16,
                                             float* __restrict__ spart) {
    __shared__ __align__(16) float sres2[2 * 4 * 16 * 17];   // 8704 B
    Ctx cx = make_ctx(blockIdx.x, threadIdx.x);
    half8_t Wf[4];
    loadWf(W16, cx, Wf);
    phaseAm0(cx, u16, spart, Wf, sres2);
}

// ---- k_Afm: softmax prologue (no max-sub; |delta| <= ~6 analytically) with
// Wf hoisted to kernel top and h=0 au loads issued pre-barrier -> the MFMA
// section's memory latency hides under the prologue / barrier. ----
__global__ __launch_bounds__(256) void k_Afm(const _Float16* __restrict__ u16,
                                             const _Float16* __restrict__ W16,
                                             const _Float16* __restrict__ delta,
                                             float* __restrict__ spart) {
    __shared__ __align__(16) float sres2[2 * 4 * 16 * 17];   // 8704 B
    __shared__ __align__(16) float ctile[BG * CTP];          // 8448 B
    Ctx cx = make_ctx(blockIdx.x, threadIdx.x);
    int l = cx.lane, w = cx.w;
    int drow = l & 15, ksub = l >> 4;

    // Wf loads issue first: L2 latency hides under the softmax prologue
    half8_t Wf[4];
    loadWf(W16, cx, Wf);

    // softmax prologue: 1024 half2-slots, 4 per thread; NO max-subtraction
    // (exp args bounded by ~|6|: f32-safe, analytically identical result)
#pragma unroll
    for (int q = 0; q < 4; ++q) {
        int slot = q * 256 + cx.tid;       // 0..1023
        int bb = slot >> 5;                // 0..31
        int s2 = slot & 31;                // half2 index within 64-i row
        int b = cx.b0 + bb;
        const _Float16* dp = delta + (size_t)b * NJ * NI + cx.i0 + s2 * 2;
        float x0[NJ], x1[NJ];
        float s0 = 0.f, s1 = 0.f;
#pragma unroll
        for (int jj = 0; jj < NJ; ++jj) {
            half2_t h = *(const half2_t*)(dp + (size_t)jj * NI);
            x0[jj] = __expf((float)h[0]); s0 += x0[jj];
            x1[jj] = __expf((float)h[1]); s1 += x1[jj];
        }
        float2 cw; cw.x = x0[cx.j] / s0; cw.y = x1[cx.j] / s1;
        *(float2*)&ctile[bb * CTP + s2 * 2] = cw;
    }

    // h=0 au loads issued BEFORE the barrier (overlap barrier wait)
    half8_t au0[4];
    {
        int b = cx.b0 + drow;
#pragma unroll
        for (int qq = 0; qq < 4; ++qq) {
            int il = w * 16 + qq * 4 + ksub;
            au0[qq] = *(const half8_t*)(u16 + ((size_t)b * NI + cx.i0 + il) * DI);
        }
    }
    __syncthreads();

    // h = 0: c-scale + MFMA
    {
        f32x4 acc = {0.f, 0.f, 0.f, 0.f};
#pragma unroll
        for (int qq = 0; qq < 4; ++qq) {
            int il = w * 16 + qq * 4 + ksub;
            _Float16 ch = (_Float16)ctile[drow * CTP + il];
            half8_t cc = {ch, ch, ch, ch, ch, ch, ch, ch};
            acc = __builtin_amdgcn_mfma_f32_16x16x32_f16(au0[qq] * cc, Wf[qq], acc, 0, 0, 0);
        }
#pragma unroll
        for (int r = 0; r < 4; ++r)
            sres2[((0 * 4 + w) * 16 + ksub * 4 + r) * 17 + drow] = acc[r];
    }
    // h = 1: load, c-scale, MFMA
    {
        int b = cx.b0 + 16 + drow;
        half8_t au1[4];
#pragma unroll
        for (int qq = 0; qq < 4; ++qq) {
            int il = w * 16 + qq * 4 + ksub;
            au1[qq] = *(const half8_t*)(u16 + ((size_t)b * NI + cx.i0 + il) * DI);
        }
        f32x4 acc = {0.f, 0.f, 0.f, 0.f};
#pragma unroll
        for (int qq = 0; qq < 4; ++qq) {
            int il = w * 16 + qq * 4 + ksub;
            _Float16 ch = (_Float16)ctile[(16 + drow) * CTP + il];
            half8_t cc = {ch, ch, ch, ch, ch, ch, ch, ch};
            acc = __builtin_amdgcn_mfma_f32_16x16x32_f16(au1[qq] * cc, Wf[qq], acc, 0, 0, 0);
        }
#pragma unroll
        for (int r = 0; r < 4; ++r)
            sres2[((1 * 4 + w) * 16 + ksub * 4 + r) * 17 + drow] = acc[r];
    }
    __syncthreads();

    // reduce 4 wave-partials; coalesced spart writes
#pragma unroll
    for (int p = 0; p < 2; ++p) {
        int idx = p * 256 + cx.tid;
        int d = idx & 15, brow = (idx >> 4) & 15, h = idx >> 8;
        float s = 0.f;
#pragma unroll
        for (int w2 = 0; w2 < 4; ++w2)
            s += sres2[((h * 4 + w2) * 16 + brow) * 17 + d];
        spart[(((size_t)cx.chunk * BB + cx.b0 + h * 16 + brow) * NJ + cx.j) * DJ + d] = s;
    }
}

// ---- k_BV: v = squash(sum_ch spart) (vectorized prologue), then
//      delta16 (+)= v . uhat ----
__global__ __launch_bounds__(256) void k_BV(const _Float16* __restrict__ u16,
                                            const _Float16* __restrict__ W16,
                                            const float* __restrict__ spart,
                                            _Float16* __restrict__ delta, int accum) {
    __shared__ __align__(16) float vsm[BG * DJ];       // 2 KB
    __shared__ __align__(16) float bres[BG * CHUNK];   // 8 KB
    Ctx cx = make_ctx(blockIdx.x, threadIdx.x);
    half8_t Wh[4];
    loadW16(W16, cx, Wh);

    // prefetch grp0 u BEFORE the squash prologue (prologue covers the latency)
    half8_t puA[4];
#pragma unroll
    for (int s2 = 0; s2 < 4; ++s2) {
        int b = cx.b0 + s2;
        puA[s2] = *(const half8_t*)(u16 + ((size_t)b * NI + cx.i0 + cx.il) * DI);
    }

    // squash prologue, vectorized: 128 threads, (bb = tid>>2, dq2 = tid&3),
    // 18 float4 loads each; ||s||^2 via in-register dot + 2 quad-DPP adds.
    if (cx.tid < 128) {
        int bb = cx.tid >> 2, dq2 = cx.tid & 3;
        int b = cx.b0 + bb;
        float4 s4 = {0.f, 0.f, 0.f, 0.f};
#pragma unroll
        for (int ch = 0; ch < NCHUNK; ++ch) {
            float4 t = *(const float4*)&spart[(((size_t)ch * BB + b) * NJ + cx.j) * DJ + dq2 * 4];
            s4.x += t.x; s4.y += t.y; s4.z += t.z; s4.w += t.w;
        }
        float sq = s4.x * s4.x + s4.y * s4.y + s4.z * s4.z + s4.w * s4.w;
        sq = dpp_add<0x0B1>(sq);   // lane^1 (quad)
        sq = dpp_add<0x04E>(sq);   // lane^2 (quad)
        float scale = (sq / (1.f + sq)) / sqrtf(sq + 1e-7f);
        float4 vv; vv.x = s4.x * scale; vv.y = s4.y * scale;
        vv.z = s4.z * scale; vv.w = s4.w * scale;
        *(float4*)&vsm[bb * DJ + dq2 * 4] = vv;
    }
    __syncthreads();

#pragma unroll
    for (int grp = 0; grp < 8; ++grp) {
        half8_t puB[4];
        if (grp < 7) {
#pragma unroll
            for (int s2 = 0; s2 < 4; ++s2) {
                int b = cx.b0 + (grp + 1) * 4 + s2;
                puB[s2] = *(const half8_t*)(u16 + ((size_t)b * NI + cx.i0 + cx.il) * DI);
            }
        }
#pragma unroll
        for (int s2 = 0; s2 < 4; ++s2) {
            int bb = grp * 4 + s2;
            float4 vv = *(const float4*)&vsm[bb * DJ + cx.dq * 4];
            float p = vv.x * dot16(Wh[0], puA[s2]);
            p = fmaf(vv.y, dot16(Wh[1], puA[s2]), p);
            p = fmaf(vv.z, dot16(Wh[2], puA[s2]), p);
            p = fmaf(vv.w, dot16(Wh[3], puA[s2]), p);
            p = dpp_add<0x0B1>(p);   // lane^1
            p = dpp_add<0x04E>(p);   // lane^2
            if (cx.dq == 0) bres[bb * CHUNK + cx.il] = p;
        }
        if (grp < 7) {
#pragma unroll
            for (int s2 = 0; s2 < 4; ++s2) puA[s2] = puB[s2];
        }
    }

    __syncthreads();
    // epilogue: 4 halves per thread (8B), coalesced 128B per bb-row; f32 accum
#pragma unroll
    for (int h = 0; h < 2; ++h) {
        int bb = (cx.tid >> 4) + 16 * h;
        int q  = cx.tid & 15;
        float4 val = ((const float4*)(bres + bb * CHUNK))[q];
        _Float16* dst = delta + (((size_t)(cx.b0 + bb) * NJ + cx.j) * NI + cx.i0) + q * 4;
        half4_t o;
        if (accum) {
            half4_t old = *(const half4_t*)dst;
            o[0] = (_Float16)(val.x + (float)old[0]);
            o[1] = (_Float16)(val.y + (float)old[1]);
            o[2] = (_Float16)(val.z + (float)old[2]);
            o[3] = (_Float16)(val.w + (float)old[3]);
        } else {
            o[0] = (_Float16)val.x; o[1] = (_Float16)val.y;
            o[2] = (_Float16)val.z; o[3] = (_Float16)val.w;
        }
        *(half4_t*)dst = o;
    }
}

// ---- k_V: out = squash(sum_ch spart), vectorized: 40 blocks x 256 ----
__global__ __launch_bounds__(256) void k_V(const float* __restrict__ spart,
                                           float* __restrict__ out) {
    int idx4 = blockIdx.x * 256 + threadIdx.x;   // 0..10239 ; covers (b,j,dq)
    float4 s4 = {0.f, 0.f, 0.f, 0.f};
#pragma unroll
    for (int ch = 0; ch < NCHUNK; ++ch) {
        float4 t = *(const float4*)&spart[(size_t)ch * (BB * NJ * DJ) + (size_t)idx4 * 4];
        s4.x += t.x; s4.y += t.y; s4.z += t.z; s4.w += t.w;
    }
    float sq = s4.x * s4.x + s4.y * s4.y + s4.z * s4.z + s4.w * s4.w;
    sq = dpp_add<0x0B1>(sq);   // quad lanes = the 4 dq of one (b,j)
    sq = dpp_add<0x04E>(sq);
    float scale = (sq / (1.f + sq)) / sqrtf(sq + 1e-7f);
    float4 o; o.x = s4.x * scale; o.y = s4.y * scale;
    o.z = s4.z * scale; o.w = s4.w * scale;
    *(float4*)&out[(size_t)idx4 * 4] = o;
}

extern "C" void kernel_launch(void* const* d_in, const int* in_sizes, int n_in,
                              void* d_out, int out_size, void* d_ws, size_t ws_size,
                              hipStream_t stream) {
    const float* u = (const float*)d_in[0];   // (256,1152,8)
    const float* W = (const float*)d_in[1];   // (10,1152,16,8)
    float* out = (float*)d_out;               // (256,10,16)

    float*     spart = (float*)d_ws;                              // NCHUNK*BB*NJ*DJ f32
    _Float16*  delta = (_Float16*)(spart + (size_t)NCHUNK * BB * NJ * DJ);  // BB*NJ*NI f16
    _Float16*  u16   = delta + (size_t)BB * NJ * NI;
    _Float16*  W16   = u16 + (size_t)BB * NI * DI;

    dim3 blk(256);
    const int GRID_CVT = ((BB * NI * DI) / 4 + (NJ * NI * DJ * DI) / 4) / (256 * 4);  // 936

    // convert inputs to f16 (deterministic, every call)
    k_cvt<<<GRID_CVT, blk, 0, stream>>>(u, W, u16, W16);
    // 6 routing launches: A0m -> BV0 -> Afm -> BV1 -> Afm -> V
    k_A0m<<<GRID_MAIN, blk, 0, stream>>>(u16, W16, spart);
    k_BV<<<GRID_MAIN, blk, 0, stream>>>(u16, W16, spart, delta, 0);
    k_Afm<<<GRID_MAIN, blk, 0, stream>>>(u16, W16, delta, spart);
    k_BV<<<GRID_MAIN, blk, 0, stream>>>(u16, W16, spart, delta, 1);
    k_Afm<<<GRID_MAIN, blk, 0, stream>>>(u16, W16, delta, spart);
    k_V<<<40, blk, 0, stream>>>(spart, out);
}

// Round 18
// 76.795 us; speedup vs baseline: 1.1005x; 1.1005x over previous
//
#include <hip/hip_runtime.h>
#include <math.h>

// Problem constants (CapsNet routing)
#define BB   256   // batch
#define NI   1152  // input capsules
#define DI   8     // input dim
#define NJ   10    // output capsules
#define DJ   16    // output dim
#define NCHUNK 18  // NI / CHUNK
#define CHUNK  64  // i per block
#define BG     32  // batch per A0m block
#define NBG    8   // BB / BG
#define GRID_MAIN (NJ * NCHUNK * NBG)   // 1440 = 8 XCD x 180
#define BG2   8    // batch per BSA block
#define GRID_BSA (8 * NCHUNK * (32 / 8))  // 576 = 8 XCD x 72
#define CTP2 68    // ctile row pad (f16)

typedef _Float16 half2_t __attribute__((ext_vector_type(2)));
typedef _Float16 half4_t __attribute__((ext_vector_type(4)));
typedef _Float16 half8_t __attribute__((ext_vector_type(8)));
typedef float    f32x4   __attribute__((ext_vector_type(4)));

// DPP cross-lane adds (VALU pipe)
// 0x0B1 quad_perm lane^1, 0x04E quad_perm lane^2
template <int CTRL>
__device__ __forceinline__ float dpp_add(float x) {
    int xi = __float_as_int(x);
    int yi = __builtin_amdgcn_update_dpp(0, xi, CTRL, 0xF, 0xF, true);
    return x + __int_as_float(yi);
}

// f16 dot-8 with f32 accumulation: 4 chained v_dot2_f32_f16
__device__ __forceinline__ float dot16(half8_t w, half8_t uu) {
    half2_t w0 = {w[0], w[1]}, w1 = {w[2], w[3]}, w2 = {w[4], w[5]}, w3 = {w[6], w[7]};
    half2_t a0 = {uu[0], uu[1]}, a1 = {uu[2], uu[3]}, a2 = {uu[4], uu[5]}, a3 = {uu[6], uu[7]};
    float acc = __builtin_amdgcn_fdot2(w0, a0, 0.f, false);
    acc = __builtin_amdgcn_fdot2(w1, a1, acc, false);
    acc = __builtin_amdgcn_fdot2(w2, a2, acc, false);
    acc = __builtin_amdgcn_fdot2(w3, a3, acc, false);
    return acc;
}

struct Ctx {
    int j, chunk, bg, i0, b0, tid, il, dq, lane, w, g, xcd, local;
};

// A0m swizzle (unchanged, proven): xcd owns bg == xcd, all (j,chunk)
__device__ __forceinline__ Ctx make_ctx(int bid, int tid) {
    Ctx c;
    c.xcd = bid & 7; c.local = bid >> 3;
    int gx = c.xcd * (GRID_MAIN / 8) + c.local;
    c.j = gx % NJ; int r = gx / NJ;
    c.chunk = r % NCHUNK; c.bg = r / NCHUNK;
    c.i0 = c.chunk * CHUNK; c.b0 = c.bg * BG;
    c.tid = tid; c.il = tid >> 2; c.dq = tid & 3;
    c.lane = tid & 63; c.w = tid >> 6; c.g = (c.lane >> 4) & 3;
    return c;
}

// MFMA-layout W fragment
__device__ __forceinline__ void loadWf(const _Float16* __restrict__ W16, const Ctx& cx,
                                       half8_t* Wf) {
    int drow = cx.lane & 15, ksub = cx.lane >> 4;
#pragma unroll
    for (int qq = 0; qq < 4; ++qq) {
        int i = cx.i0 + cx.w * 16 + qq * 4 + ksub;
        Wf[qq] = *(const half8_t*)(W16 + (((size_t)cx.j * NI + i) * DJ + drow) * DI);
    }
}

// ---- f32 -> f16 conversion, 4 float4 per thread (grid 936) ----
__global__ __launch_bounds__(256) void k_cvt(const float* __restrict__ uf,
                                             const float* __restrict__ Wf,
                                             _Float16* __restrict__ u16,
                                             _Float16* __restrict__ W16) {
    const int nu4 = (BB * NI * DI) / 4;
    int base = (blockIdx.x * 256 + threadIdx.x) * 4;
    if (base < nu4) {
#pragma unroll
        for (int t = 0; t < 4; ++t) {
            float4 v = ((const float4*)uf)[base + t];
            half4_t h = {(_Float16)v.x, (_Float16)v.y, (_Float16)v.z, (_Float16)v.w};
            ((half4_t*)u16)[base + t] = h;
        }
    } else {
        int k = base - nu4;
#pragma unroll
        for (int t = 0; t < 4; ++t) {
            float4 v = ((const float4*)Wf)[k + t];
            half4_t h = {(_Float16)v.x, (_Float16)v.y, (_Float16)v.z, (_Float16)v.w};
            ((half4_t*)W16)[k + t] = h;
        }
    }
}

// ---- k_A0m: iter-0 A phase, MFMA, c=0.1 exact (unchanged from r17) ----
__global__ __launch_bounds__(256) void k_A0m(const _Float16* __restrict__ u16,
                                             const _Float16* __restrict__ W16,
                                             float* __restrict__ spart) {
    __shared__ __align__(16) float sres2[2 * 4 * 16 * 17];
    Ctx cx = make_ctx(blockIdx.x, threadIdx.x);
    half8_t Wf[4];
    loadWf(W16, cx, Wf);
    int l = cx.lane, w = cx.w;
    int drow = l & 15, ksub = l >> 4;

    half8_t au[2][4];
#pragma unroll
    for (int h = 0; h < 2; ++h) {
        int b = cx.b0 + h * 16 + drow;
#pragma unroll
        for (int qq = 0; qq < 4; ++qq) {
            int il = w * 16 + qq * 4 + ksub;
            au[h][qq] = *(const half8_t*)(u16 + ((size_t)b * NI + cx.i0 + il) * DI);
        }
    }
#pragma unroll
    for (int h = 0; h < 2; ++h) {
        f32x4 acc = {0.f, 0.f, 0.f, 0.f};
#pragma unroll
        for (int qq = 0; qq < 4; ++qq)
            acc = __builtin_amdgcn_mfma_f32_16x16x32_f16(au[h][qq], Wf[qq], acc, 0, 0, 0);
#pragma unroll
        for (int r = 0; r < 4; ++r)
            sres2[((h * 4 + w) * 16 + ksub * 4 + r) * 17 + drow] = acc[r];
    }
    __syncthreads();
#pragma unroll
    for (int p = 0; p < 2; ++p) {
        int idx = p * 256 + cx.tid;
        int d = idx & 15, brow = (idx >> 4) & 15, h = idx >> 8;
        float s = 0.f;
#pragma unroll
        for (int w2 = 0; w2 < 4; ++w2)
            s += sres2[((h * 4 + w2) * 16 + brow) * 17 + d];
        s *= 0.1f;
        spart[(((size_t)cx.chunk * BB + cx.b0 + h * 16 + brow) * NJ + cx.j) * DJ + d] = s;
    }
}

// ---- k_BSA: fused {squash -> B(delta) -> softmax -> A(spart)} for all 10 j.
// Block = (xcd, chunk, bgl): 8 batches x 64 i x all j. 4 barriers, j-loops
// barrier-free. u loaded once per phase and reused across j. ----
template <int ACCUM>
__global__ __launch_bounds__(256) void k_BSA(const _Float16* __restrict__ u16,
                                             const _Float16* __restrict__ W16,
                                             float* __restrict__ spart,
                                             _Float16* __restrict__ delta) {
    __shared__ __align__(16) float     vsm[BG2 * NJ * DJ];        // 5120 B
    __shared__ __align__(16) _Float16  dtile[BG2 * NJ * CHUNK];   // 10240 B
    __shared__ __align__(16) _Float16  ctile[NJ * BG2 * CTP2];    // 10880 B
    __shared__ __align__(16) float     sres[NJ * 4 * 8 * 17];     // 21760 B

    int xcd = blockIdx.x & 7, local = blockIdx.x >> 3;   // local 0..71
    int chunk = local % NCHUNK;
    int bgl   = local / NCHUNK;                          // 0..3
    int b0 = xcd * 32 + bgl * BG2;
    int i0 = chunk * CHUNK;
    int tid = threadIdx.x;
    int lane = tid & 63, w = tid >> 6;

    // ---- phase 1: v[b8][j][:] = squash(sum_ch spart) ; 320 slots ----
#pragma unroll
    for (int p = 0; p < 2; ++p) {
        int slot = p * 256 + tid;
        if (slot < BG2 * NJ * 4) {                       // 320
            int b8 = slot / 40, rem = slot - b8 * 40;
            int j = rem >> 2, dq2 = rem & 3;
            int b = b0 + b8;
            float4 s4 = {0.f, 0.f, 0.f, 0.f};
#pragma unroll
            for (int ch = 0; ch < NCHUNK; ++ch) {
                float4 t = *(const float4*)&spart[(((size_t)ch * BB + b) * NJ + j) * DJ + dq2 * 4];
                s4.x += t.x; s4.y += t.y; s4.z += t.z; s4.w += t.w;
            }
            float sq = s4.x * s4.x + s4.y * s4.y + s4.z * s4.z + s4.w * s4.w;
            sq = dpp_add<0x0B1>(sq);   // quads = dq2 groups (40 % 4 == 0)
            sq = dpp_add<0x04E>(sq);
            float scale = (sq / (1.f + sq)) / sqrtf(sq + 1e-7f);
            float4 vv; vv.x = s4.x * scale; vv.y = s4.y * scale;
            vv.z = s4.z * scale; vv.w = s4.w * scale;
            *(float4*)&vsm[(b8 * NJ + j) * DJ + dq2 * 4] = vv;
        }
    }
    __syncthreads();

    // ---- phase 2: B for each j; raw pj -> dtile ----
    int il = tid >> 2, dq = tid & 3;
    half8_t pu[BG2];
#pragma unroll
    for (int b8 = 0; b8 < BG2; ++b8)
        pu[b8] = *(const half8_t*)(u16 + ((size_t)(b0 + b8) * NI + i0 + il) * DI);

    for (int j = 0; j < NJ; ++j) {
        half8_t Wh[4];
        const half8_t* wp = (const half8_t*)(W16 +
            (((size_t)j * NI + i0 + il) * DJ + dq * 4) * DI);
#pragma unroll
        for (int q = 0; q < 4; ++q) Wh[q] = wp[q];
        float pj[BG2];
#pragma unroll
        for (int b8 = 0; b8 < BG2; ++b8) {
            float4 vv = *(const float4*)&vsm[(b8 * NJ + j) * DJ + dq * 4];
            float p = vv.x * dot16(Wh[0], pu[b8]);
            p = fmaf(vv.y, dot16(Wh[1], pu[b8]), p);
            p = fmaf(vv.z, dot16(Wh[2], pu[b8]), p);
            p = fmaf(vv.w, dot16(Wh[3], pu[b8]), p);
            p = dpp_add<0x0B1>(p);
            p = dpp_add<0x04E>(p);
            pj[b8] = p;
        }
        if (dq == 0) {
#pragma unroll
            for (int b8 = 0; b8 < BG2; ++b8)
                dtile[(b8 * NJ + j) * CHUNK + il] = (_Float16)pj[b8];
        }
    }
    __syncthreads();

    // ---- pack phase: delta global (coalesced half4, RMW if ACCUM) ;
    //      accumulated value written back to dtile for softmax ----
#pragma unroll
    for (int p = 0; p < 5; ++p) {
        int slot = p * 256 + tid;                        // 0..1279
        int i4 = slot & 15, j = (slot >> 4) % NJ, b8 = slot / (NJ * 16);
        _Float16* dst = delta + (((size_t)(b0 + b8) * NJ + j) * NI + i0) + i4 * 4;
        half4_t raw = *(const half4_t*)&dtile[(b8 * NJ + j) * CHUNK + i4 * 4];
        if (ACCUM) {
            half4_t old = *(const half4_t*)dst;
            half4_t nw;
#pragma unroll
            for (int t = 0; t < 4; ++t) nw[t] = (_Float16)((float)raw[t] + (float)old[t]);
            *(half4_t*)dst = nw;
            *(half4_t*)&dtile[(b8 * NJ + j) * CHUNK + i4 * 4] = nw;
        } else {
            *(half4_t*)dst = raw;
        }
    }
    __syncthreads();

    // ---- phase 3: softmax over j from dtile -> ctile (f16) ----
#pragma unroll
    for (int p = 0; p < 2; ++p) {
        int pair = p * 256 + tid;                        // 0..511
        int b8 = pair >> 6, i = pair & 63;
        float x[NJ]; float ssum = 0.f;
#pragma unroll
        for (int j = 0; j < NJ; ++j) {
            x[j] = __expf((float)dtile[(b8 * NJ + j) * CHUNK + i]);  // |delta|<~12: safe
            ssum += x[j];
        }
        float rs = 1.f / ssum;
#pragma unroll
        for (int j = 0; j < NJ; ++j)
            ctile[(j * BG2 + b8) * CTP2 + i] = (_Float16)(x[j] * rs);
    }
    __syncthreads();

    // ---- phase 4: MFMA A per j (rows 8..15 idle); sres, then epilogue ----
    int drow = lane & 15, ksub = lane >> 4;
    bool brow_ok = drow < BG2;
    half8_t au0[4];
#pragma unroll
    for (int qq = 0; qq < 4; ++qq) {
        int ili = w * 16 + qq * 4 + ksub;
        au0[qq] = brow_ok
            ? *(const half8_t*)(u16 + ((size_t)(b0 + drow) * NI + i0 + ili) * DI)
            : (half8_t){0, 0, 0, 0, 0, 0, 0, 0};
    }
    for (int j = 0; j < NJ; ++j) {
        half8_t Wfj[4];
#pragma unroll
        for (int qq = 0; qq < 4; ++qq) {
            int i = i0 + w * 16 + qq * 4 + ksub;
            Wfj[qq] = *(const half8_t*)(W16 + (((size_t)j * NI + i) * DJ + drow) * DI);
        }
        f32x4 acc = {0.f, 0.f, 0.f, 0.f};
#pragma unroll
        for (int qq = 0; qq < 4; ++qq) {
            int ili = w * 16 + qq * 4 + ksub;
            _Float16 ch = brow_ok ? ctile[(j * BG2 + drow) * CTP2 + ili] : (_Float16)0.f;
            half8_t cc = {ch, ch, ch, ch, ch, ch, ch, ch};
            acc = __builtin_amdgcn_mfma_f32_16x16x32_f16(au0[qq] * cc, Wfj[qq], acc, 0, 0, 0);
        }
        if (ksub < 2) {                                  // output rows 0..7
#pragma unroll
            for (int r = 0; r < 4; ++r)
                sres[((j * 4 + w) * 8 + ksub * 4 + r) * 17 + drow] = acc[r];
        }
    }
    __syncthreads();
#pragma unroll
    for (int p = 0; p < 5; ++p) {
        int idx = p * 256 + tid;                         // 0..1279
        int d = idx & 15, brow = (idx >> 4) & 7, j = idx >> 7;
        float s = 0.f;
#pragma unroll
        for (int w2 = 0; w2 < 4; ++w2)
            s += sres[((j * 4 + w2) * 8 + brow) * 17 + d];
        spart[(((size_t)chunk * BB + b0 + brow) * NJ + j) * DJ + d] = s;
    }
}

// ---- k_V: out = squash(sum_ch spart), vectorized: 40 blocks x 256 ----
__global__ __launch_bounds__(256) void k_V(const float* __restrict__ spart,
                                           float* __restrict__ out) {
    int idx4 = blockIdx.x * 256 + threadIdx.x;
    float4 s4 = {0.f, 0.f, 0.f, 0.f};
#pragma unroll
    for (int ch = 0; ch < NCHUNK; ++ch) {
        float4 t = *(const float4*)&spart[(size_t)ch * (BB * NJ * DJ) + (size_t)idx4 * 4];
        s4.x += t.x; s4.y += t.y; s4.z += t.z; s4.w += t.w;
    }
    float sq = s4.x * s4.x + s4.y * s4.y + s4.z * s4.z + s4.w * s4.w;
    sq = dpp_add<0x0B1>(sq);
    sq = dpp_add<0x04E>(sq);
    float scale = (sq / (1.f + sq)) / sqrtf(sq + 1e-7f);
    float4 o; o.x = s4.x * scale; o.y = s4.y * scale;
    o.z = s4.z * scale; o.w = s4.w * scale;
    *(float4*)&out[(size_t)idx4 * 4] = o;
}

extern "C" void kernel_launch(void* const* d_in, const int* in_sizes, int n_in,
                              void* d_out, int out_size, void* d_ws, size_t ws_size,
                              hipStream_t stream) {
    const float* u = (const float*)d_in[0];   // (256,1152,8)
    const float* W = (const float*)d_in[1];   // (10,1152,16,8)
    float* out = (float*)d_out;               // (256,10,16)

    float*     spart = (float*)d_ws;                              // NCHUNK*BB*NJ*DJ f32
    _Float16*  delta = (_Float16*)(spart + (size_t)NCHUNK * BB * NJ * DJ);  // BB*NJ*NI f16
    _Float16*  u16   = delta + (size_t)BB * NJ * NI;
    _Float16*  W16   = u16 + (size_t)BB * NI * DI;

    dim3 blk(256);
    const int GRID_CVT = ((BB * NI * DI) / 4 + (NJ * NI * DJ * DI) / 4) / (256 * 4);  // 936

    // 5 launches: cvt -> A0m -> BSA(t0) -> BSA(t1) -> V
    k_cvt<<<GRID_CVT, blk, 0, stream>>>(u, W, u16, W16);
    k_A0m<<<GRID_MAIN, blk, 0, stream>>>(u16, W16, spart);
    k_BSA<0><<<GRID_BSA, blk, 0, stream>>>(u16, W16, spart, delta);
    k_BSA<1><<<GRID_BSA, blk, 0, stream>>>(u16, W16, spart, delta);
    k_V<<<40, blk, 0, stream>>>(spart, out);
}

// Round 19
// 75.996 us; speedup vs baseline: 1.1120x; 1.0105x over previous
//
#include <hip/hip_runtime.h>
#include <math.h>

// Problem constants (CapsNet routing)
#define BB   256   // batch
#define NI   1152  // input capsules
#define DI   8     // input dim
#define NJ   10    // output capsules
#define DJ   16    // output dim
#define NCHUNK 18  // NI / CHUNK
#define CHUNK  64  // i per block
#define BG     32  // batch per A0m block
#define NBG    8   // BB / BG
#define GRID_MAIN (NJ * NCHUNK * NBG)   // 1440 = 8 XCD x 180
#define BG2   8    // batch per BSA block
#define GRID_BSA (8 * NCHUNK * (32 / 8))  // 576 = 8 XCD x 72
#define CTP2 68    // ctile row pad (f16)

typedef _Float16 half2_t __attribute__((ext_vector_type(2)));
typedef _Float16 half4_t __attribute__((ext_vector_type(4)));
typedef _Float16 half8_t __attribute__((ext_vector_type(8)));
typedef float    f32x4   __attribute__((ext_vector_type(4)));

// DPP cross-lane adds (VALU pipe)
// 0x0B1 quad_perm lane^1, 0x04E quad_perm lane^2
template <int CTRL>
__device__ __forceinline__ float dpp_add(float x) {
    int xi = __float_as_int(x);
    int yi = __builtin_amdgcn_update_dpp(0, xi, CTRL, 0xF, 0xF, true);
    return x + __int_as_float(yi);
}

// f16 dot-8 with f32 accumulation: 4 chained v_dot2_f32_f16
__device__ __forceinline__ float dot16(half8_t w, half8_t uu) {
    half2_t w0 = {w[0], w[1]}, w1 = {w[2], w[3]}, w2 = {w[4], w[5]}, w3 = {w[6], w[7]};
    half2_t a0 = {uu[0], uu[1]}, a1 = {uu[2], uu[3]}, a2 = {uu[4], uu[5]}, a3 = {uu[6], uu[7]};
    float acc = __builtin_amdgcn_fdot2(w0, a0, 0.f, false);
    acc = __builtin_amdgcn_fdot2(w1, a1, acc, false);
    acc = __builtin_amdgcn_fdot2(w2, a2, acc, false);
    acc = __builtin_amdgcn_fdot2(w3, a3, acc, false);
    return acc;
}

struct Ctx {
    int j, chunk, bg, i0, b0, tid, il, dq, lane, w, g, xcd, local;
};

// A0m swizzle (proven): xcd owns bg == xcd, all (j,chunk)
__device__ __forceinline__ Ctx make_ctx(int bid, int tid) {
    Ctx c;
    c.xcd = bid & 7; c.local = bid >> 3;
    int gx = c.xcd * (GRID_MAIN / 8) + c.local;
    c.j = gx % NJ; int r = gx / NJ;
    c.chunk = r % NCHUNK; c.bg = r / NCHUNK;
    c.i0 = c.chunk * CHUNK; c.b0 = c.bg * BG;
    c.tid = tid; c.il = tid >> 2; c.dq = tid & 3;
    c.lane = tid & 63; c.w = tid >> 6; c.g = (c.lane >> 4) & 3;
    return c;
}

// MFMA-layout W fragment
__device__ __forceinline__ void loadWf(const _Float16* __restrict__ W16, const Ctx& cx,
                                       half8_t* Wf) {
    int drow = cx.lane & 15, ksub = cx.lane >> 4;
#pragma unroll
    for (int qq = 0; qq < 4; ++qq) {
        int i = cx.i0 + cx.w * 16 + qq * 4 + ksub;
        Wf[qq] = *(const half8_t*)(W16 + (((size_t)cx.j * NI + i) * DJ + drow) * DI);
    }
}

// ---- f32 -> f16 conversion, 4 float4 per thread (grid 936) ----
__global__ __launch_bounds__(256) void k_cvt(const float* __restrict__ uf,
                                             const float* __restrict__ Wf,
                                             _Float16* __restrict__ u16,
                                             _Float16* __restrict__ W16) {
    const int nu4 = (BB * NI * DI) / 4;
    int base = (blockIdx.x * 256 + threadIdx.x) * 4;
    if (base < nu4) {
#pragma unroll
        for (int t = 0; t < 4; ++t) {
            float4 v = ((const float4*)uf)[base + t];
            half4_t h = {(_Float16)v.x, (_Float16)v.y, (_Float16)v.z, (_Float16)v.w};
            ((half4_t*)u16)[base + t] = h;
        }
    } else {
        int k = base - nu4;
#pragma unroll
        for (int t = 0; t < 4; ++t) {
            float4 v = ((const float4*)Wf)[k + t];
            half4_t h = {(_Float16)v.x, (_Float16)v.y, (_Float16)v.z, (_Float16)v.w};
            ((half4_t*)W16)[k + t] = h;
        }
    }
}

// ---- k_A0m: iter-0 A phase, MFMA, c=0.1 exact (unchanged, proven) ----
__global__ __launch_bounds__(256) void k_A0m(const _Float16* __restrict__ u16,
                                             const _Float16* __restrict__ W16,
                                             float* __restrict__ spart) {
    __shared__ __align__(16) float sres2[2 * 4 * 16 * 17];
    Ctx cx = make_ctx(blockIdx.x, threadIdx.x);
    half8_t Wf[4];
    loadWf(W16, cx, Wf);
    int l = cx.lane, w = cx.w;
    int drow = l & 15, ksub = l >> 4;

    half8_t au[2][4];
#pragma unroll
    for (int h = 0; h < 2; ++h) {
        int b = cx.b0 + h * 16 + drow;
#pragma unroll
        for (int qq = 0; qq < 4; ++qq) {
            int il = w * 16 + qq * 4 + ksub;
            au[h][qq] = *(const half8_t*)(u16 + ((size_t)b * NI + cx.i0 + il) * DI);
        }
    }
#pragma unroll
    for (int h = 0; h < 2; ++h) {
        f32x4 acc = {0.f, 0.f, 0.f, 0.f};
#pragma unroll
        for (int qq = 0; qq < 4; ++qq)
            acc = __builtin_amdgcn_mfma_f32_16x16x32_f16(au[h][qq], Wf[qq], acc, 0, 0, 0);
#pragma unroll
        for (int r = 0; r < 4; ++r)
            sres2[((h * 4 + w) * 16 + ksub * 4 + r) * 17 + drow] = acc[r];
    }
    __syncthreads();
#pragma unroll
    for (int p = 0; p < 2; ++p) {
        int idx = p * 256 + cx.tid;
        int d = idx & 15, brow = (idx >> 4) & 15, h = idx >> 8;
        float s = 0.f;
#pragma unroll
        for (int w2 = 0; w2 < 4; ++w2)
            s += sres2[((h * 4 + w2) * 16 + brow) * 17 + d];
        s *= 0.1f;
        spart[(((size_t)cx.chunk * BB + cx.b0 + h * 16 + brow) * NJ + cx.j) * DJ + d] = s;
    }
}

// ---- k_BSA: fused {squash -> B -> softmax -> A} for all 10 j.
// ITER=0: v = v1; chunk==0 blocks persist v1 to vbuf.
// ITER=1: v = v1 + vbuf (= v0+v1), so the B phase produces the TOTAL delta
// directly (b_ij = (v0+v1).uhat since b starts at 0) -- no global delta array,
// no RMW, no pack phase. u-loads hoisted to top; W fragments double-buffered
// across the j loops.
template <int ITER>
__global__ __launch_bounds__(256) void k_BSA(const _Float16* __restrict__ u16,
                                             const _Float16* __restrict__ W16,
                                             float* __restrict__ spart,
                                             float* __restrict__ vbuf) {
    __shared__ __align__(16) float     vsm[BG2 * NJ * DJ];        // 5120 B
    __shared__ __align__(16) _Float16  dtile[BG2 * NJ * CHUNK];   // 10240 B
    __shared__ __align__(16) _Float16  ctile[NJ * BG2 * CTP2];    // 10880 B
    __shared__ __align__(16) float     sres[NJ * 4 * 8 * 17];     // 21760 B

    int xcd = blockIdx.x & 7, local = blockIdx.x >> 3;   // local 0..71
    int chunk = local % NCHUNK;
    int bgl   = local / NCHUNK;                          // 0..3
    int b0 = xcd * 32 + bgl * BG2;
    int i0 = chunk * CHUNK;
    int tid = threadIdx.x;
    int lane = tid & 63, w = tid >> 6;
    int il = tid >> 2, dq = tid & 3;
    int drow = lane & 15, ksub = lane >> 4;
    bool brow_ok = drow < BG2;

    // ---- early u-loads (independent of phase 1; latency hides under squash)
    half8_t pu[BG2];                                     // phase-2 layout
#pragma unroll
    for (int b8 = 0; b8 < BG2; ++b8)
        pu[b8] = *(const half8_t*)(u16 + ((size_t)(b0 + b8) * NI + i0 + il) * DI);
    half8_t au0[4];                                      // phase-4 layout
#pragma unroll
    for (int qq = 0; qq < 4; ++qq) {
        int ili = w * 16 + qq * 4 + ksub;
        au0[qq] = brow_ok
            ? *(const half8_t*)(u16 + ((size_t)(b0 + drow) * NI + i0 + ili) * DI)
            : (half8_t){0, 0, 0, 0, 0, 0, 0, 0};
    }

    // ---- phase 1: v1 = squash(sum_ch spart); vtot per ITER ----
#pragma unroll
    for (int p = 0; p < 2; ++p) {
        int slot = p * 256 + tid;
        if (slot < BG2 * NJ * 4) {                       // 320
            int b8 = slot / 40, rem = slot - b8 * 40;
            int j = rem >> 2, dq2 = rem & 3;
            int b = b0 + b8;
            float4 s4 = {0.f, 0.f, 0.f, 0.f};
#pragma unroll
            for (int ch = 0; ch < NCHUNK; ++ch) {
                float4 t = *(const float4*)&spart[(((size_t)ch * BB + b) * NJ + j) * DJ + dq2 * 4];
                s4.x += t.x; s4.y += t.y; s4.z += t.z; s4.w += t.w;
            }
            float sq = s4.x * s4.x + s4.y * s4.y + s4.z * s4.z + s4.w * s4.w;
            sq = dpp_add<0x0B1>(sq);   // quads align with dq2 (40 % 4 == 0)
            sq = dpp_add<0x04E>(sq);
            float scale = (sq / (1.f + sq)) / sqrtf(sq + 1e-7f);
            float4 vv; vv.x = s4.x * scale; vv.y = s4.y * scale;
            vv.z = s4.z * scale; vv.w = s4.w * scale;
            size_t va = ((size_t)b * NJ + j) * DJ + dq2 * 4;
            if (ITER == 0) {
                if (chunk == 0) *(float4*)&vbuf[va] = vv;   // persist v0
            } else {
                float4 v0 = *(const float4*)&vbuf[va];      // vtot = v0 + v1
                vv.x += v0.x; vv.y += v0.y; vv.z += v0.z; vv.w += v0.w;
            }
            *(float4*)&vsm[(b8 * NJ + j) * DJ + dq2 * 4] = vv;
        }
    }
    __syncthreads();

    // ---- phase 2: B for each j (vtot . uhat) -> dtile; Wh double-buffered ----
    half8_t WhA[4], WhB[4];
    {
        const half8_t* wp = (const half8_t*)(W16 + (((size_t)0 * NI + i0 + il) * DJ + dq * 4) * DI);
#pragma unroll
        for (int q = 0; q < 4; ++q) WhA[q] = wp[q];
    }
    for (int j = 0; j < NJ; ++j) {
        if (j + 1 < NJ) {
            const half8_t* wp = (const half8_t*)(W16 +
                (((size_t)(j + 1) * NI + i0 + il) * DJ + dq * 4) * DI);
#pragma unroll
            for (int q = 0; q < 4; ++q) WhB[q] = wp[q];
        }
        float pj[BG2];
#pragma unroll
        for (int b8 = 0; b8 < BG2; ++b8) {
            float4 vv = *(const float4*)&vsm[(b8 * NJ + j) * DJ + dq * 4];
            float p = vv.x * dot16(WhA[0], pu[b8]);
            p = fmaf(vv.y, dot16(WhA[1], pu[b8]), p);
            p = fmaf(vv.z, dot16(WhA[2], pu[b8]), p);
            p = fmaf(vv.w, dot16(WhA[3], pu[b8]), p);
            p = dpp_add<0x0B1>(p);
            p = dpp_add<0x04E>(p);
            pj[b8] = p;
        }
        if (dq == 0) {
#pragma unroll
            for (int b8 = 0; b8 < BG2; ++b8)
                dtile[(b8 * NJ + j) * CHUNK + il] = (_Float16)pj[b8];
        }
        if (j + 1 < NJ) {
#pragma unroll
            for (int q = 0; q < 4; ++q) WhA[q] = WhB[q];
        }
    }
    __syncthreads();

    // ---- phase 3: softmax over j from dtile -> ctile (f16; no max-sub,
    //      |delta| <= ~12 analytically: f32-exp safe) ----
#pragma unroll
    for (int p = 0; p < 2; ++p) {
        int pair = p * 256 + tid;                        // 0..511
        int b8 = pair >> 6, i = pair & 63;
        float x[NJ]; float ssum = 0.f;
#pragma unroll
        for (int j = 0; j < NJ; ++j) {
            x[j] = __expf((float)dtile[(b8 * NJ + j) * CHUNK + i]);
            ssum += x[j];
        }
        float rs = 1.f / ssum;
#pragma unroll
        for (int j = 0; j < NJ; ++j)
            ctile[(j * BG2 + b8) * CTP2 + i] = (_Float16)(x[j] * rs);
    }
    __syncthreads();

    // ---- phase 4: MFMA A per j (rows 8..15 idle); Wfj double-buffered ----
    half8_t WfA[4], WfB[4];
#pragma unroll
    for (int qq = 0; qq < 4; ++qq) {
        int i = i0 + w * 16 + qq * 4 + ksub;
        WfA[qq] = *(const half8_t*)(W16 + (((size_t)0 * NI + i) * DJ + drow) * DI);
    }
    for (int j = 0; j < NJ; ++j) {
        if (j + 1 < NJ) {
#pragma unroll
            for (int qq = 0; qq < 4; ++qq) {
                int i = i0 + w * 16 + qq * 4 + ksub;
                WfB[qq] = *(const half8_t*)(W16 + (((size_t)(j + 1) * NI + i) * DJ + drow) * DI);
            }
        }
        f32x4 acc = {0.f, 0.f, 0.f, 0.f};
#pragma unroll
        for (int qq = 0; qq < 4; ++qq) {
            int ili = w * 16 + qq * 4 + ksub;
            _Float16 ch = brow_ok ? ctile[(j * BG2 + drow) * CTP2 + ili] : (_Float16)0.f;
            half8_t cc = {ch, ch, ch, ch, ch, ch, ch, ch};
            acc = __builtin_amdgcn_mfma_f32_16x16x32_f16(au0[qq] * cc, WfA[qq], acc, 0, 0, 0);
        }
        if (ksub < 2) {                                  // output rows 0..7
#pragma unroll
            for (int r = 0; r < 4; ++r)
                sres[((j * 4 + w) * 8 + ksub * 4 + r) * 17 + drow] = acc[r];
        }
        if (j + 1 < NJ) {
#pragma unroll
            for (int qq = 0; qq < 4; ++qq) WfA[qq] = WfB[qq];
        }
    }
    __syncthreads();
#pragma unroll
    for (int p = 0; p < 5; ++p) {
        int idx = p * 256 + tid;                         // 0..1279
        int d = idx & 15, brow2 = (idx >> 4) & 7, j = idx >> 7;
        float s = 0.f;
#pragma unroll
        for (int w2 = 0; w2 < 4; ++w2)
            s += sres[((j * 4 + w2) * 8 + brow2) * 17 + d];
        spart[(((size_t)chunk * BB + b0 + brow2) * NJ + j) * DJ + d] = s;
    }
}

// ---- k_V: out = squash(sum_ch spart), vectorized: 40 blocks x 256 ----
__global__ __launch_bounds__(256) void k_V(const float* __restrict__ spart,
                                           float* __restrict__ out) {
    int idx4 = blockIdx.x * 256 + threadIdx.x;
    float4 s4 = {0.f, 0.f, 0.f, 0.f};
#pragma unroll
    for (int ch = 0; ch < NCHUNK; ++ch) {
        float4 t = *(const float4*)&spart[(size_t)ch * (BB * NJ * DJ) + (size_t)idx4 * 4];
        s4.x += t.x; s4.y += t.y; s4.z += t.z; s4.w += t.w;
    }
    float sq = s4.x * s4.x + s4.y * s4.y + s4.z * s4.z + s4.w * s4.w;
    sq = dpp_add<0x0B1>(sq);
    sq = dpp_add<0x04E>(sq);
    float scale = (sq / (1.f + sq)) / sqrtf(sq + 1e-7f);
    float4 o; o.x = s4.x * scale; o.y = s4.y * scale;
    o.z = s4.z * scale; o.w = s4.w * scale;
    *(float4*)&out[(size_t)idx4 * 4] = o;
}

extern "C" void kernel_launch(void* const* d_in, const int* in_sizes, int n_in,
                              void* d_out, int out_size, void* d_ws, size_t ws_size,
                              hipStream_t stream) {
    const float* u = (const float*)d_in[0];   // (256,1152,8)
    const float* W = (const float*)d_in[1];   // (10,1152,16,8)
    float* out = (float*)d_out;               // (256,10,16)

    float*     spart = (float*)d_ws;                              // NCHUNK*BB*NJ*DJ f32
    float*     vbuf  = spart + (size_t)NCHUNK * BB * NJ * DJ;     // BB*NJ*DJ f32
    _Float16*  u16   = (_Float16*)(vbuf + (size_t)BB * NJ * DJ);
    _Float16*  W16   = u16 + (size_t)BB * NI * DI;

    dim3 blk(256);
    const int GRID_CVT = ((BB * NI * DI) / 4 + (NJ * NI * DJ * DI) / 4) / (256 * 4);  // 936

    // 5 launches: cvt -> A0m -> BSA(t0) -> BSA(t1) -> V
    k_cvt<<<GRID_CVT, blk, 0, stream>>>(u, W, u16, W16);
    k_A0m<<<GRID_MAIN, blk, 0, stream>>>(u16, W16, spart);
    k_BSA<0><<<GRID_BSA, blk, 0, stream>>>(u16, W16, spart, vbuf);
    k_BSA<1><<<GRID_BSA, blk, 0, stream>>>(u16, W16, spart, vbuf);
    k_V<<<40, blk, 0, stream>>>(spart, out);
}